// Round 5
// baseline (6873.997 us; speedup 1.0000x reference)
//
#include <hip/hip_runtime.h>
#include <math.h>

#define B 8
#define P 2048
#define D 64
#define EPS 0.1f
#define INVEPS 10.0f
#define MAXIT 100
#define THRESH 0.1f
#define RSLAB 8                    // rows per slab (8 waves x 1 row)
#define ROWS_PER_BLK 32            // 4 slabs per block
#define NBLK_A (B * P / ROWS_PER_BLK)   // 512 blocks
#define PLANES (P / ROWS_PER_BLK)       // 64 partial planes per batch

#define S2F   14.4269504089f       // 10 * log2(e)   (scale into exp2 domain)
#define NS2F (-14.4269504089f)
#define EPSLN2 0.069314718056f     // EPS * ln(2)

// exp2/log2: avoid __exp2f/__log2f spellings (collide with glibc math.h
// internal decls). Use AMDGCN builtins (v_exp_f32 / v_log_f32) on device.
#if defined(__AMDGCN__) && __has_builtin(__builtin_amdgcn_exp2f)
#define EXP2F(x) __builtin_amdgcn_exp2f(x)
#else
#define EXP2F(x) exp2f(x)
#endif
#if defined(__AMDGCN__) && __has_builtin(__builtin_amdgcn_logf)
#define LOG2F(x) __builtin_amdgcn_logf(x)
#else
#define LOG2F(x) log2f(x)
#endif

// Raw barrier: waits LDS ops only — does NOT drain vmcnt, so register
// prefetch loads stay in flight across slab boundaries (the compiler's
// __syncthreads emits s_waitcnt vmcnt(0) which serializes the pipeline).
__device__ __forceinline__ void block_sync_lgkm() {
    asm volatile("s_waitcnt lgkmcnt(0)\n\ts_barrier" ::: "memory");
}

// ---------------- C build: C[b,i,j] = sum_d (x[b,i,d]-y[b,j,d])^2 ----------
__global__ __launch_bounds__(256) void build_C(const float* __restrict__ x,
                                               const float* __restrict__ y,
                                               float* __restrict__ C) {
    __shared__ float xs[64 * 68];
    __shared__ float ys[64 * 68];
    const int tid = threadIdx.x;
    const int blk = blockIdx.x;        // 8 * 32 * 32 = 8192 blocks
    const int b   = blk >> 10;
    const int rem = blk & 1023;
    const int i0  = (rem >> 5) << 6;
    const int j0  = (rem & 31) << 6;

    const float4* xg = (const float4*)(x + ((size_t)(b * P + i0)) * D);
    const float4* yg = (const float4*)(y + ((size_t)(b * P + j0)) * D);
#pragma unroll
    for (int p = 0; p < 4; ++p) {
        int q = tid + (p << 8);
        int row = q >> 4, c4 = q & 15;
        float4 xv = xg[row * 16 + c4];
        float4 yv = yg[row * 16 + c4];
        float* xd = &xs[row * 68 + (c4 << 2)];
        xd[0] = xv.x; xd[1] = xv.y; xd[2] = xv.z; xd[3] = xv.w;
        float* yd = &ys[row * 68 + (c4 << 2)];
        yd[0] = yv.x; yd[1] = yv.y; yd[2] = yv.z; yd[3] = yv.w;
    }
    __syncthreads();

    const int ti = tid >> 4, tj = tid & 15;
    float acc[4][4] = {};
#pragma unroll 4
    for (int d4 = 0; d4 < 16; ++d4) {
        float4 xa[4], yb[4];
#pragma unroll
        for (int a = 0; a < 4; ++a)
            xa[a] = *(const float4*)&xs[(ti * 4 + a) * 68 + (d4 << 2)];
#pragma unroll
        for (int bb = 0; bb < 4; ++bb)
            yb[bb] = *(const float4*)&ys[(tj * 4 + bb) * 68 + (d4 << 2)];
#pragma unroll
        for (int a = 0; a < 4; ++a)
#pragma unroll
            for (int bb = 0; bb < 4; ++bb) {
                float dx = xa[a].x - yb[bb].x;
                float dy = xa[a].y - yb[bb].y;
                float dz = xa[a].z - yb[bb].z;
                float dw = xa[a].w - yb[bb].w;
                acc[a][bb] += dx * dx + dy * dy + dz * dz + dw * dw;
            }
    }
    size_t base = ((size_t)b * P + (i0 + ti * 4)) * P + (j0 + tj * 4);
#pragma unroll
    for (int a = 0; a < 4; ++a) {
        float4 o = make_float4(acc[a][0], acc[a][1], acc[a][2], acc[a][3]);
        *(float4*)&C[base + (size_t)a * P] = o;
    }
}

// -------- online logsumexp helpers (exp2 domain: m=max(z2), s=sum 2^(z2-m)) ----
__device__ __forceinline__ void lse_push2(float z, float& m, float& s) {
    float d = z - m;
    float w = EXP2F(-fabsf(d));       // 2^(min-max); first push: d=+inf -> w=0
    bool gt = d > 0.0f;
    m = gt ? z : m;
    s = fmaf(s, gt ? w : 1.0f, gt ? 1.0f : w);
}
__device__ __forceinline__ void lse_merge2(float mo, float so, float& m, float& s) {
    float M = fmaxf(m, mo);
    s = s * EXP2F(m - M) + so * EXP2F(mo - M);
    m = M;
}

// ---------------- init: zero u, v, err accumulators, done flags, cost ------
__global__ void init_ws(float* __restrict__ u, float* __restrict__ v,
                        float* __restrict__ errAcc, unsigned* __restrict__ doneArr,
                        float* __restrict__ cost) {
    int idx = blockIdx.x * blockDim.x + threadIdx.x;
    if (idx < B * P) { u[idx] = 0.0f; v[idx] = 0.0f; }
    if (idx < MAXIT) errAcc[idx] = 0.0f;
    if (idx <= MAXIT) doneArr[idx] = 0u;
    if (idx < B) cost[idx] = 0.0f;
}

// ---- iteration kernel A: row-LSE then column partials, deep pipeline ------
// 512 threads = 8 waves; wave owns 1 row per slab, 4 slabs. Register double-
// buffer (pfA/pfB): the NEXT slab's row loads are issued at the TOP of the
// current slab's row phase, so they are in flight across the entire slab
// (row phase + 2 raw barriers + col phase ~ 1500 cyc >> HBM/L3 latency).
// Barriers wait lgkmcnt only — global loads are never drained.
template <bool MORE>
__device__ __forceinline__ void slab_body(
        const float* __restrict__ Cb, const float* __restrict__ sv,
        float* __restrict__ sC, float* __restrict__ su,
        float* __restrict__ u, int b, int r, int lane, int wid, int tid,
        float4 (&cur)[8], float4 (&nxt)[8],
        float (&cm)[4], float (&cs)[4], float& werr, float eps_logmu) {
    // 1. issue next-slab prefetch (row r+8) into the other register buffer
    if (MORE) {
        const float4* CrowN = (const float4*)(Cb + (size_t)(r + RSLAB) * P);
#pragma unroll
        for (int k = 0; k < 8; ++k) nxt[k] = CrowN[lane + (k << 6)];
    }
    // 2. row-LSE from cur; stage row into sC for the col phase
    float4* lrow = (float4*)&sC[wid * P];
    float rm[4] = {-INFINITY, -INFINITY, -INFINITY, -INFINITY};
    float rs[4] = {0.0f, 0.0f, 0.0f, 0.0f};
#pragma unroll
    for (int k = 0; k < 8; ++k) {
        float4 c4 = cur[k];
        lrow[lane + (k << 6)] = c4;
        float4 v4 = ((const float4*)sv)[lane + (k << 6)];
        lse_push2(fmaf(c4.x, NS2F, v4.x), rm[0], rs[0]);
        lse_push2(fmaf(c4.y, NS2F, v4.y), rm[1], rs[1]);
        lse_push2(fmaf(c4.z, NS2F, v4.z), rm[2], rs[2]);
        lse_push2(fmaf(c4.w, NS2F, v4.w), rm[3], rs[3]);
    }
    lse_merge2(rm[1], rs[1], rm[0], rs[0]);
    lse_merge2(rm[3], rs[3], rm[2], rs[2]);
    lse_merge2(rm[2], rs[2], rm[0], rs[0]);
#pragma unroll
    for (int off = 32; off; off >>= 1) {
        float mo = __shfl_xor(rm[0], off, 64);
        float so = __shfl_xor(rs[0], off, 64);
        lse_merge2(mo, so, rm[0], rs[0]);
    }
    float unew = eps_logmu - EPSLN2 * (rm[0] + LOG2F(rs[0]));
    if (lane == 0) {
        int gi = b * P + r;
        werr += fabsf(unew - u[gi]);
        u[gi] = unew;
        su[wid] = unew;
    }
    // 3. publish sC + su (LDS only; prefetch loads stay in flight)
    block_sync_lgkm();
    // 4. col pushes: thread owns cols 4*tid..4*tid+3, 8 rows from LDS
#pragma unroll
    for (int rr = 0; rr < RSLAB; ++rr) {
        float u2 = su[rr] * S2F;
        float4 c4 = *(const float4*)&sC[rr * P + (tid << 2)];
        lse_push2(fmaf(c4.x, NS2F, u2), cm[0], cs[0]);
        lse_push2(fmaf(c4.y, NS2F, u2), cm[1], cs[1]);
        lse_push2(fmaf(c4.z, NS2F, u2), cm[2], cs[2]);
        lse_push2(fmaf(c4.w, NS2F, u2), cm[3], cs[3]);
    }
    // 5. protect sC/su before next slab overwrites
    block_sync_lgkm();
}

__global__ __launch_bounds__(512, 4) void iter_rowcol(
        const float* __restrict__ C, const float* __restrict__ vg,
        float* __restrict__ u, float2* __restrict__ part,
        float* __restrict__ errAcc, const unsigned* __restrict__ doneArr, int t) {
    if (doneArr[t]) return;
    __shared__ float sC[RSLAB * P];   // 64 KB: current slab's rows
    __shared__ float sv[P];           // 8 KB: this batch's v (exp2-scaled)
    __shared__ float su[RSLAB];
    __shared__ float serr[8];
    const int tid = threadIdx.x, lane = tid & 63, wid = tid >> 6;  // 8 waves
    const int b  = blockIdx.x >> 6;       // 64 blocks per batch
    const int q  = blockIdx.x & 63;       // row-block within batch
    const int r0 = q * ROWS_PER_BLK;
    const float* Cb = C + (size_t)b * P * P;
    const float eps_logmu = EPS * logf(1.0f / (float)P + 1e-8f);

    // stage scaled v: 512 threads x float4
    {
        float4 vv = ((const float4*)(vg + (size_t)b * P))[tid];
        vv.x *= S2F; vv.y *= S2F; vv.z *= S2F; vv.w *= S2F;
        ((float4*)sv)[tid] = vv;
    }

    // prefetch slab 0: wave `wid` owns row r0 + wid
    float4 pfA[8], pfB[8];
    {
        const float4* Crow = (const float4*)(Cb + (size_t)(r0 + wid) * P);
#pragma unroll
        for (int k = 0; k < 8; ++k) pfA[k] = Crow[lane + (k << 6)];
    }

    float cm[4], cs[4];                   // col chains: cols 4*tid..+3
#pragma unroll
    for (int c = 0; c < 4; ++c) { cm[c] = -INFINITY; cs[c] = 0.0f; }
    float werr = 0.0f;
    block_sync_lgkm();                    // sv ready

    const int rb = r0 + wid;
    slab_body<true >(Cb, sv, sC, su, u, b, rb,      lane, wid, tid, pfA, pfB, cm, cs, werr, eps_logmu);
    slab_body<true >(Cb, sv, sC, su, u, b, rb + 8,  lane, wid, tid, pfB, pfA, cm, cs, werr, eps_logmu);
    slab_body<true >(Cb, sv, sC, su, u, b, rb + 16, lane, wid, tid, pfA, pfB, cm, cs, werr, eps_logmu);
    slab_body<false>(Cb, sv, sC, su, u, b, rb + 24, lane, wid, tid, pfB, pfA, cm, cs, werr, eps_logmu);

    if (lane == 0) serr[wid] = werr;
    block_sync_lgkm();
    if (tid == 0)
        atomicAdd(&errAcc[t], serr[0] + serr[1] + serr[2] + serr[3] +
                              serr[4] + serr[5] + serr[6] + serr[7]);

    // ---- store partial plane q for batch b (coalesced float4) ----
    float2* pbase = part + ((size_t)q * B + b) * P;
    *(float4*)&pbase[(tid << 2)]     = make_float4(cm[0], cs[0], cm[1], cs[1]);
    *(float4*)&pbase[(tid << 2) + 2] = make_float4(cm[2], cs[2], cm[3], cs[3]);
}

// ---- iteration kernel B: merge 64 planes -> v; latch done flag ------------
// 256 blocks x 256 threads; a block owns 64 columns; 4 threads per column,
// each merging 16 planes (2 independent chains), then LDS tree-reduce.
// Chain state is exp2-domain (m = max z2, s = sum 2^(z2-m)).
__global__ __launch_bounds__(256) void iter_merge(
        const float2* __restrict__ part, float* __restrict__ vg,
        const float* __restrict__ errAcc, unsigned* __restrict__ doneArr, int t) {
    __shared__ float2 sred[3][64];
    const int tid = threadIdx.x;
    if (blockIdx.x == 0 && tid == 0) {
        // errAcc[t]==0 when frozen, so the latch self-propagates.
        doneArr[t + 1] = doneArr[t] | (errAcc[t] < THRESH * (float)B ? 1u : 0u);
    }
    if (doneArr[t]) return;
    const int cl = tid & 63;              // column within block
    const int g  = tid >> 6;              // plane group 0..3
    const size_t idx = (size_t)blockIdx.x * 64 + cl;   // global column
    float m[2] = {-INFINITY, -INFINITY}, s[2] = {0.0f, 0.0f};
#pragma unroll
    for (int k = 0; k < 8; ++k) {
#pragma unroll
        for (int c = 0; c < 2; ++c) {
            int qq = g * 16 + k * 2 + c;
            float2 pk = part[(size_t)qq * (B * P) + idx];
            lse_merge2(pk.x, pk.y, m[c], s[c]);
        }
    }
    lse_merge2(m[1], s[1], m[0], s[0]);
    if (g) sred[g - 1][cl] = make_float2(m[0], s[0]);
    __syncthreads();
    if (g == 0) {
#pragma unroll
        for (int gg = 0; gg < 3; ++gg) {
            float2 o = sred[gg][cl];
            lse_merge2(o.x, o.y, m[0], s[0]);
        }
        const float eps_logmu = EPS * logf(1.0f / (float)P + 1e-8f);  // log_nu == log_mu
        vg[idx] = eps_logmu - EPSLN2 * (m[0] + LOG2F(s[0]));
    }
}

// ---- final: pi = exp((u+v-C)/eps), cost[b] = sum pi*C ---------------------
// 1024 blocks * 4 waves * 4 rows = 16384 rows = B*P.
__global__ __launch_bounds__(256) void final_pi_cost(
        const float* __restrict__ C, const float* __restrict__ u,
        const float* __restrict__ vg, float* __restrict__ pi,
        float* __restrict__ cost) {
    __shared__ float sc[B];
    const int tid = threadIdx.x, lane = tid & 63, wid = tid >> 6;
    if (tid < B) sc[tid] = 0.0f;
    __syncthreads();
    const int gw = blockIdx.x * 4 + wid;      // 0..4095
    const int rbase = gw * 4;
    if (rbase >= B * P) return;               // defensive
    const int b = rbase >> 11;
    const float4* vrow = (const float4*)(vg + b * P);
    float acc = 0.0f;
    for (int k = 0; k < 4; ++k) {
        const int r = rbase + k;
        const float ur = u[r];
        const float4* Crow = (const float4*)(C + (size_t)r * P);
        float4* prow = (float4*)(pi + (size_t)r * P);
        for (int it = lane; it < P / 4; it += 64) {
            float4 c4 = Crow[it];
            float4 v4 = vrow[it];
            float4 p4;
            p4.x = __expf((ur + v4.x - c4.x) * INVEPS);
            p4.y = __expf((ur + v4.y - c4.y) * INVEPS);
            p4.z = __expf((ur + v4.z - c4.z) * INVEPS);
            p4.w = __expf((ur + v4.w - c4.w) * INVEPS);
            prow[it] = p4;
            acc += p4.x * c4.x + p4.y * c4.y + p4.z * c4.z + p4.w * c4.w;
        }
    }
#pragma unroll
    for (int off = 32; off; off >>= 1) acc += __shfl_xor(acc, off, 64);
    if (lane == 0) atomicAdd(&sc[b], acc);
    __syncthreads();
    if (tid < B && sc[tid] != 0.0f) atomicAdd(&cost[tid], sc[tid]);
}

extern "C" void kernel_launch(void* const* d_in, const int* in_sizes, int n_in,
                              void* d_out, int out_size, void* d_ws, size_t ws_size,
                              hipStream_t stream) {
    const float* x = (const float*)d_in[0];
    const float* y = (const float*)d_in[1];
    float* out  = (float*)d_out;
    float* cost = out;                              // [8]
    float* pi   = out + 8;                          // [8*2048*2048]
    float* C    = out + 8 + (size_t)B * P * P;      // [8*2048*2048]

    // Column partials live in the pi output region (scratch until final pass):
    // PLANES * B*P float2 = 8 MB << 134 MB.
    float2* part = (float2*)pi;

    float* ws      = (float*)d_ws;
    float* u       = ws;                            // B*P
    float* v       = ws + B * P;                    // B*P
    float* errAcc  = ws + 2 * B * P;                // MAXIT
    unsigned* doneArr = (unsigned*)(ws + 2 * B * P + 128);  // MAXIT+1

    hipLaunchKernelGGL(build_C, dim3(8 * 32 * 32), dim3(256), 0, stream, x, y, C);
    hipLaunchKernelGGL(init_ws, dim3(64), dim3(256), 0, stream,
                       u, v, errAcc, doneArr, cost);

    for (int t = 0; t < MAXIT; ++t) {
        hipLaunchKernelGGL(iter_rowcol, dim3(NBLK_A), dim3(512), 0, stream,
                           (const float*)C, (const float*)v, u, part,
                           errAcc, (const unsigned*)doneArr, t);
        hipLaunchKernelGGL(iter_merge, dim3(B * P / 64), dim3(256), 0, stream,
                           (const float2*)part, v, (const float*)errAcc,
                           doneArr, t);
    }

    hipLaunchKernelGGL(final_pi_cost, dim3(1024), dim3(256), 0, stream,
                       (const float*)C, (const float*)u, (const float*)v,
                       pi, cost);
}

// Round 6
// 4580.215 us; speedup vs baseline: 1.5008x; 1.5008x over previous
//
#include <hip/hip_runtime.h>
#include <math.h>

#define B 8
#define P 2048
#define D 64
#define EPS 0.1f
#define INVEPS 10.0f
#define MAXIT 100
#define THRESH 0.1f
#define NBLK_A 512                 // 64 row-blocks x 8 batches
#define PLANES 64                  // partial planes per batch

#define S2F    14.4269504089f      // 10 * log2(e)  (into exp2 domain)
#define TWOS2F 28.8539008177f      // 2 * S2F
#define EPSLN2 0.069314718056f     // EPS * ln(2)

// exp2/log2: avoid __exp2f/__log2f spellings (collide with glibc math.h
// internal decls). Use AMDGCN builtins (v_exp_f32 / v_log_f32) on device.
#if defined(__AMDGCN__) && __has_builtin(__builtin_amdgcn_exp2f)
#define EXP2F(x) __builtin_amdgcn_exp2f(x)
#else
#define EXP2F(x) exp2f(x)
#endif
#if defined(__AMDGCN__) && __has_builtin(__builtin_amdgcn_logf)
#define LOG2F(x) __builtin_amdgcn_logf(x)
#else
#define LOG2F(x) log2f(x)
#endif

typedef _Float16 f16x8 __attribute__((ext_vector_type(8)));
typedef float    f32x4 __attribute__((ext_vector_type(4)));

// ---------------- C build: C[b,i,j] = sum_d (x[b,i,d]-y[b,j,d])^2 ----------
// (C is a required OUTPUT and is used by final_pi_cost; iterations no longer
// read it.)
__global__ __launch_bounds__(256) void build_C(const float* __restrict__ x,
                                               const float* __restrict__ y,
                                               float* __restrict__ C) {
    __shared__ float xs[64 * 68];
    __shared__ float ys[64 * 68];
    const int tid = threadIdx.x;
    const int blk = blockIdx.x;        // 8 * 32 * 32 = 8192 blocks
    const int b   = blk >> 10;
    const int rem = blk & 1023;
    const int i0  = (rem >> 5) << 6;
    const int j0  = (rem & 31) << 6;

    const float4* xg = (const float4*)(x + ((size_t)(b * P + i0)) * D);
    const float4* yg = (const float4*)(y + ((size_t)(b * P + j0)) * D);
#pragma unroll
    for (int p = 0; p < 4; ++p) {
        int q = tid + (p << 8);
        int row = q >> 4, c4 = q & 15;
        float4 xv = xg[row * 16 + c4];
        float4 yv = yg[row * 16 + c4];
        float* xd = &xs[row * 68 + (c4 << 2)];
        xd[0] = xv.x; xd[1] = xv.y; xd[2] = xv.z; xd[3] = xv.w;
        float* yd = &ys[row * 68 + (c4 << 2)];
        yd[0] = yv.x; yd[1] = yv.y; yd[2] = yv.z; yd[3] = yv.w;
    }
    __syncthreads();

    const int ti = tid >> 4, tj = tid & 15;
    float acc[4][4] = {};
#pragma unroll 4
    for (int d4 = 0; d4 < 16; ++d4) {
        float4 xa[4], yb[4];
#pragma unroll
        for (int a = 0; a < 4; ++a)
            xa[a] = *(const float4*)&xs[(ti * 4 + a) * 68 + (d4 << 2)];
#pragma unroll
        for (int bb = 0; bb < 4; ++bb)
            yb[bb] = *(const float4*)&ys[(tj * 4 + bb) * 68 + (d4 << 2)];
#pragma unroll
        for (int a = 0; a < 4; ++a)
#pragma unroll
            for (int bb = 0; bb < 4; ++bb) {
                float dx = xa[a].x - yb[bb].x;
                float dy = xa[a].y - yb[bb].y;
                float dz = xa[a].z - yb[bb].z;
                float dw = xa[a].w - yb[bb].w;
                acc[a][bb] += dx * dx + dy * dy + dz * dz + dw * dw;
            }
    }
    size_t base = ((size_t)b * P + (i0 + ti * 4)) * P + (j0 + tj * 4);
#pragma unroll
    for (int a = 0; a < 4; ++a) {
        float4 o = make_float4(acc[a][0], acc[a][1], acc[a][2], acc[a][3]);
        *(float4*)&C[base + (size_t)a * P] = o;
    }
}

// -------- online logsumexp helpers (exp2 domain: m=max(z2), s=sum 2^(z2-m)) ----
__device__ __forceinline__ void lse_push2(float z, float& m, float& s) {
    float d = z - m;
    float w = EXP2F(-fabsf(d));       // 2^(min-max); first push: d=+inf -> w=0
    bool gt = d > 0.0f;
    m = gt ? z : m;
    s = fmaf(s, gt ? w : 1.0f, gt ? 1.0f : w);
}
__device__ __forceinline__ void lse_merge2(float mo, float so, float& m, float& s) {
    float M = fmaxf(m, mo);
    s = s * EXP2F(m - M) + so * EXP2F(mo - M);
    m = M;
}

// ---- setup: fp16 copies of x,y + squared norms + initial w2 = -yn*S2F -----
// block 256 thr handles 32 points; 8 lanes per point (8 d's each).
__global__ __launch_bounds__(256) void setup_half(
        const float* __restrict__ x, const float* __restrict__ y,
        _Float16* __restrict__ xh, _Float16* __restrict__ yh,
        float* __restrict__ xn, float* __restrict__ yn,
        float* __restrict__ w2g) {
    const int tid = threadIdx.x;
    const int pt  = blockIdx.x * 32 + (tid >> 3);   // 0..B*P-1
    const int l8  = tid & 7;
    const size_t off = (size_t)pt * D + l8 * 8;
    float4 a0 = *(const float4*)(x + off);
    float4 a1 = *(const float4*)(x + off + 4);
    f16x8 hx;
    hx[0]=(_Float16)a0.x; hx[1]=(_Float16)a0.y; hx[2]=(_Float16)a0.z; hx[3]=(_Float16)a0.w;
    hx[4]=(_Float16)a1.x; hx[5]=(_Float16)a1.y; hx[6]=(_Float16)a1.z; hx[7]=(_Float16)a1.w;
    *(f16x8*)(xh + off) = hx;
    float nx = a0.x*a0.x + a0.y*a0.y + a0.z*a0.z + a0.w*a0.w
             + a1.x*a1.x + a1.y*a1.y + a1.z*a1.z + a1.w*a1.w;
    float4 b0 = *(const float4*)(y + off);
    float4 b1 = *(const float4*)(y + off + 4);
    f16x8 hy;
    hy[0]=(_Float16)b0.x; hy[1]=(_Float16)b0.y; hy[2]=(_Float16)b0.z; hy[3]=(_Float16)b0.w;
    hy[4]=(_Float16)b1.x; hy[5]=(_Float16)b1.y; hy[6]=(_Float16)b1.z; hy[7]=(_Float16)b1.w;
    *(f16x8*)(yh + off) = hy;
    float ny = b0.x*b0.x + b0.y*b0.y + b0.z*b0.z + b0.w*b0.w
             + b1.x*b1.x + b1.y*b1.y + b1.z*b1.z + b1.w*b1.w;
#pragma unroll
    for (int o = 1; o < 8; o <<= 1) {
        nx += __shfl_xor(nx, o, 8);
        ny += __shfl_xor(ny, o, 8);
    }
    if (l8 == 0) { xn[pt] = nx; yn[pt] = ny; w2g[pt] = -ny * S2F; }
}

// ---------------- init: zero u, v, err accumulators, done flags, cost ------
__global__ void init_ws(float* __restrict__ u, float* __restrict__ v,
                        float* __restrict__ errAcc, unsigned* __restrict__ doneArr,
                        float* __restrict__ cost) {
    int idx = blockIdx.x * blockDim.x + threadIdx.x;
    if (idx < B * P) { u[idx] = 0.0f; v[idx] = 0.0f; }
    if (idx < MAXIT) errAcc[idx] = 0.0f;
    if (idx <= MAXIT) doneArr[idx] = 0u;
    if (idx < B) cost[idx] = 0.0f;
}

// ---- iteration kernel A: MFMA-recomputed Gram, row-LSE then col partials --
// 512 blocks x 512 thr (8 waves). Block owns 32 rows of one batch, all 2048
// cols. C is NEVER read: z2 = (w_j + 2*G_ij)*S2F with G = <x_i,y_j> via
// fp16 16x16x32 MFMA (4 per 32x16 col-tile), w_j = v_j - |y_j|^2 pre-scaled.
// Row constant |x_i|^2 folds into the u finalize (EPS*10 == 1). Col phase
// recomputes G identically (bit-deterministic) -> no G storage anywhere.
__global__ __launch_bounds__(512, 4) void iter_rowcol(
        const _Float16* __restrict__ xh, const _Float16* __restrict__ yh,
        const float* __restrict__ xn, const float* __restrict__ w2g,
        float* __restrict__ u, float2* __restrict__ part,
        float* __restrict__ errAcc, const unsigned* __restrict__ doneArr, int t) {
    if (doneArr[t]) return;
    __shared__ float  sw2[P];          // 8 KB: w2 = (v - yn)*S2F for batch
    __shared__ float2 rowpart[8][32];  // per-wave row-LSE partials
    __shared__ float  sa2[32];         // (unew - xn)*S2F per row
    __shared__ float  sxr[32];         // xn for this block's rows
    const int tid = threadIdx.x, lane = tid & 63, wid = tid >> 6;
    const int lg = lane >> 4, li = lane & 15;
    const int b = blockIdx.x >> 6, q = blockIdx.x & 63;
    const int r0 = q * 32;
    const float eps_logmu = EPS * logf(1.0f / (float)P + 1e-8f);

    ((float4*)sw2)[tid] = ((const float4*)(w2g + (size_t)b * P))[tid];
    if (tid < 32) sxr[tid] = xn[b * P + r0 + tid];

    // A fragments: row = li (16 rows/tile, 2 tiles), d = kc*32 + lg*8 .. +7.
    // Same lane->d pattern for A and B => any internal k-permutation cancels.
    f16x8 Af[2][2];
#pragma unroll
    for (int mt = 0; mt < 2; ++mt)
#pragma unroll
        for (int kc = 0; kc < 2; ++kc)
            Af[mt][kc] = *(const f16x8*)(xh +
                ((size_t)(b * P + r0 + mt * 16 + li)) * D + kc * 32 + lg * 8);

    const _Float16* ybase = yh + ((size_t)(b * P + wid * 256 + li)) * D + lg * 8;

    float rm[8], rs[8];                 // row chains: c = mt*4 + reg
#pragma unroll
    for (int c = 0; c < 8; ++c) { rm[c] = -INFINITY; rs[c] = 0.0f; }

    __syncthreads();

    // ---------------- row phase: 16 col-tiles of 16 ----------------
    {
        f16x8 B0 = *(const f16x8*)(ybase);
        f16x8 B1 = *(const f16x8*)(ybase + 32);
#pragma unroll
        for (int ct = 0; ct < 16; ++ct) {
            f16x8 cB0 = B0, cB1 = B1;
            if (ct < 15) {
                B0 = *(const f16x8*)(ybase + (size_t)(ct + 1) * 16 * D);
                B1 = *(const f16x8*)(ybase + (size_t)(ct + 1) * 16 * D + 32);
            }
            f32x4 g0 = {0.f, 0.f, 0.f, 0.f}, g1 = {0.f, 0.f, 0.f, 0.f};
            g0 = __builtin_amdgcn_mfma_f32_16x16x32_f16(Af[0][0], cB0, g0, 0, 0, 0);
            g0 = __builtin_amdgcn_mfma_f32_16x16x32_f16(Af[0][1], cB1, g0, 0, 0, 0);
            g1 = __builtin_amdgcn_mfma_f32_16x16x32_f16(Af[1][0], cB0, g1, 0, 0, 0);
            g1 = __builtin_amdgcn_mfma_f32_16x16x32_f16(Af[1][1], cB1, g1, 0, 0, 0);
            // D layout: col = li (this lane's column), row = lg*4 + reg
            float w2c = sw2[wid * 256 + ct * 16 + li];
#pragma unroll
            for (int reg = 0; reg < 4; ++reg) {
                lse_push2(fmaf(g0[reg], TWOS2F, w2c), rm[reg],     rs[reg]);
                lse_push2(fmaf(g1[reg], TWOS2F, w2c), rm[4 + reg], rs[4 + reg]);
            }
        }
    }
    // merge row chains across the 16 lanes (li) of each group
#pragma unroll
    for (int off = 1; off < 16; off <<= 1)
#pragma unroll
        for (int c = 0; c < 8; ++c) {
            float mo = __shfl_xor(rm[c], off, 64);
            float so = __shfl_xor(rs[c], off, 64);
            lse_merge2(mo, so, rm[c], rs[c]);
        }
    if (li == 0) {
#pragma unroll
        for (int c = 0; c < 8; ++c)
            rowpart[wid][(c >> 2) * 16 + lg * 4 + (c & 3)] = make_float2(rm[c], rs[c]);
    }
    __syncthreads();

    // ---------------- u finalize: one row per thread (tid<32) ----------------
    if (tid < 32) {
        float m = rowpart[0][tid].x, s = rowpart[0][tid].y;
#pragma unroll
        for (int w = 1; w < 8; ++w)
            lse_merge2(rowpart[w][tid].x, rowpart[w][tid].y, m, s);
        float unew = eps_logmu + sxr[tid] - EPSLN2 * (m + LOG2F(s));
        int gi = b * P + r0 + tid;
        float e = fabsf(unew - u[gi]);
        u[gi] = unew;
        sa2[tid] = (unew - sxr[tid]) * S2F;
#pragma unroll
        for (int off = 16; off; off >>= 1) e += __shfl_xor(e, off, 32);
        if (tid == 0) atomicAdd(&errAcc[t], e);
    }
    __syncthreads();

    // ---------------- col phase: recompute G, per-ct col chains ----------------
    float a2v[8];
#pragma unroll
    for (int c = 0; c < 8; ++c) a2v[c] = sa2[(c >> 2) * 16 + lg * 4 + (c & 3)];
    float2* pbase = part + ((size_t)q * B + b) * P + wid * 256;
    {
        f16x8 B0 = *(const f16x8*)(ybase);
        f16x8 B1 = *(const f16x8*)(ybase + 32);
#pragma unroll
        for (int ct = 0; ct < 16; ++ct) {
            f16x8 cB0 = B0, cB1 = B1;
            if (ct < 15) {
                B0 = *(const f16x8*)(ybase + (size_t)(ct + 1) * 16 * D);
                B1 = *(const f16x8*)(ybase + (size_t)(ct + 1) * 16 * D + 32);
            }
            f32x4 g0 = {0.f, 0.f, 0.f, 0.f}, g1 = {0.f, 0.f, 0.f, 0.f};
            g0 = __builtin_amdgcn_mfma_f32_16x16x32_f16(Af[0][0], cB0, g0, 0, 0, 0);
            g0 = __builtin_amdgcn_mfma_f32_16x16x32_f16(Af[0][1], cB1, g0, 0, 0, 0);
            g1 = __builtin_amdgcn_mfma_f32_16x16x32_f16(Af[1][0], cB0, g1, 0, 0, 0);
            g1 = __builtin_amdgcn_mfma_f32_16x16x32_f16(Af[1][1], cB1, g1, 0, 0, 0);
            float cmL = -INFINITY, csL = 0.0f;   // chain for col li+16ct+256wid
#pragma unroll
            for (int reg = 0; reg < 4; ++reg) {
                lse_push2(fmaf(g0[reg], TWOS2F, a2v[reg]),     cmL, csL);
                lse_push2(fmaf(g1[reg], TWOS2F, a2v[4 + reg]), cmL, csL);
            }
            // merge across the 4 lanes holding this column (lg groups)
            { float mo = __shfl_xor(cmL, 16, 64), so = __shfl_xor(csL, 16, 64);
              lse_merge2(mo, so, cmL, csL); }
            { float mo = __shfl_xor(cmL, 32, 64), so = __shfl_xor(csL, 32, 64);
              lse_merge2(mo, so, cmL, csL); }
            if (lane < 16) pbase[ct * 16 + li] = make_float2(cmL, csL);
        }
    }
}

// ---- iteration kernel B: merge 64 planes -> v (+ w2 for next iter) --------
__global__ __launch_bounds__(256) void iter_merge(
        const float2* __restrict__ part, float* __restrict__ vg,
        const float* __restrict__ yn, float* __restrict__ w2g,
        const float* __restrict__ errAcc, unsigned* __restrict__ doneArr, int t) {
    __shared__ float2 sred[3][64];
    const int tid = threadIdx.x;
    if (blockIdx.x == 0 && tid == 0) {
        // errAcc[t]==0 when frozen, so the latch self-propagates.
        doneArr[t + 1] = doneArr[t] | (errAcc[t] < THRESH * (float)B ? 1u : 0u);
    }
    if (doneArr[t]) return;
    const int cl = tid & 63;              // column within block
    const int g  = tid >> 6;              // plane group 0..3
    const size_t idx = (size_t)blockIdx.x * 64 + cl;   // global column
    float m[2] = {-INFINITY, -INFINITY}, s[2] = {0.0f, 0.0f};
#pragma unroll
    for (int k = 0; k < 8; ++k) {
#pragma unroll
        for (int c = 0; c < 2; ++c) {
            int qq = g * 16 + k * 2 + c;
            float2 pk = part[(size_t)qq * (B * P) + idx];
            lse_merge2(pk.x, pk.y, m[c], s[c]);
        }
    }
    lse_merge2(m[1], s[1], m[0], s[0]);
    if (g) sred[g - 1][cl] = make_float2(m[0], s[0]);
    __syncthreads();
    if (g == 0) {
#pragma unroll
        for (int gg = 0; gg < 3; ++gg) {
            float2 o = sred[gg][cl];
            lse_merge2(o.x, o.y, m[0], s[0]);
        }
        const float eps_logmu = EPS * logf(1.0f / (float)P + 1e-8f);  // log_nu == log_mu
        float ynv  = yn[idx];
        float vnew = eps_logmu + ynv - EPSLN2 * (m[0] + LOG2F(s[0]));
        vg[idx]  = vnew;
        w2g[idx] = (vnew - ynv) * S2F;
    }
}

// ---- final: pi = exp((u+v-C)/eps), cost[b] = sum pi*C ---------------------
__global__ __launch_bounds__(256) void final_pi_cost(
        const float* __restrict__ C, const float* __restrict__ u,
        const float* __restrict__ vg, float* __restrict__ pi,
        float* __restrict__ cost) {
    __shared__ float sc[B];
    const int tid = threadIdx.x, lane = tid & 63, wid = tid >> 6;
    if (tid < B) sc[tid] = 0.0f;
    __syncthreads();
    const int gw = blockIdx.x * 4 + wid;      // 0..4095
    const int rbase = gw * 4;
    if (rbase >= B * P) return;               // defensive
    const int b = rbase >> 11;
    const float4* vrow = (const float4*)(vg + b * P);
    float acc = 0.0f;
    for (int k = 0; k < 4; ++k) {
        const int r = rbase + k;
        const float ur = u[r];
        const float4* Crow = (const float4*)(C + (size_t)r * P);
        float4* prow = (float4*)(pi + (size_t)r * P);
        for (int it = lane; it < P / 4; it += 64) {
            float4 c4 = Crow[it];
            float4 v4 = vrow[it];
            float4 p4;
            p4.x = __expf((ur + v4.x - c4.x) * INVEPS);
            p4.y = __expf((ur + v4.y - c4.y) * INVEPS);
            p4.z = __expf((ur + v4.z - c4.z) * INVEPS);
            p4.w = __expf((ur + v4.w - c4.w) * INVEPS);
            prow[it] = p4;
            acc += p4.x * c4.x + p4.y * c4.y + p4.z * c4.z + p4.w * c4.w;
        }
    }
#pragma unroll
    for (int off = 32; off; off >>= 1) acc += __shfl_xor(acc, off, 64);
    if (lane == 0) atomicAdd(&sc[b], acc);
    __syncthreads();
    if (tid < B && sc[tid] != 0.0f) atomicAdd(&cost[tid], sc[tid]);
}

extern "C" void kernel_launch(void* const* d_in, const int* in_sizes, int n_in,
                              void* d_out, int out_size, void* d_ws, size_t ws_size,
                              hipStream_t stream) {
    const float* x = (const float*)d_in[0];
    const float* y = (const float*)d_in[1];
    float* out  = (float*)d_out;
    float* cost = out;                              // [8]
    float* pi   = out + 8;                          // [8*2048*2048]
    float* C    = out + 8 + (size_t)B * P * P;      // [8*2048*2048]

    // Scratch lives in the pi output region (dead before final_pi_cost
    // overwrites the whole region):
    float2*    part = (float2*)pi;                  // 64*16384 float2 = 8 MB
    _Float16*  xh   = (_Float16*)(pi + 2097152);    // 2 MB
    _Float16*  yh   = (_Float16*)(pi + 2097152 + 524288);
    float*     xnb  = pi + 2097152 + 2 * 524288;    // B*P
    float*     ynb  = xnb + B * P;                  // B*P
    float*     w2g  = ynb + B * P;                  // B*P

    float* ws      = (float*)d_ws;
    float* u       = ws;                            // B*P
    float* v       = ws + B * P;                    // B*P
    float* errAcc  = ws + 2 * B * P;                // MAXIT
    unsigned* doneArr = (unsigned*)(ws + 2 * B * P + 128);  // MAXIT+1

    hipLaunchKernelGGL(build_C, dim3(8 * 32 * 32), dim3(256), 0, stream, x, y, C);
    hipLaunchKernelGGL(setup_half, dim3(B * P / 32), dim3(256), 0, stream,
                       x, y, xh, yh, xnb, ynb, w2g);
    hipLaunchKernelGGL(init_ws, dim3(64), dim3(256), 0, stream,
                       u, v, errAcc, doneArr, cost);

    for (int t = 0; t < MAXIT; ++t) {
        hipLaunchKernelGGL(iter_rowcol, dim3(NBLK_A), dim3(512), 0, stream,
                           (const _Float16*)xh, (const _Float16*)yh,
                           (const float*)xnb, (const float*)w2g,
                           u, part, errAcc, (const unsigned*)doneArr, t);
        hipLaunchKernelGGL(iter_merge, dim3(B * P / 64), dim3(256), 0, stream,
                           (const float2*)part, v, (const float*)ynb, w2g,
                           (const float*)errAcc, doneArr, t);
    }

    hipLaunchKernelGGL(final_pi_cost, dim3(1024), dim3(256), 0, stream,
                       (const float*)C, (const float*)u, (const float*)v,
                       pi, cost);
}